// Round 4
// baseline (94936.713 us; speedup 1.0000x reference)
//
#include <hip/hip_runtime.h>
#include <hip/hip_bf16.h>
#include <math.h>

// ---------------------------------------------------------------------------
// VRNN on MI355X — Round 4: single-launch sequential phase.
// The recurrence is batch-row-local, so one kernel (32 WGs x 16 rows) runs
// all TC timesteps: enc1->enc2->heads->z->phiz->GRU per step with only
// __syncthreads. Activations in LDS (bf16, padded rows), h in fp32 global +
// bf16 LDS, weights streamed from global (L2). Pre/post phases stay as
// Round-3 MFMA GEMMs. Chunked ws plan (TC adaptive) retained.
// ---------------------------------------------------------------------------

typedef __attribute__((ext_vector_type(8))) short bfrag;   // 8 x bf16
typedef __attribute__((ext_vector_type(4))) float ffrag;   // 4 x f32
typedef __hip_bfloat16 bf16;

#define MFMA16(a,b,c) __builtin_amdgcn_mfma_f32_16x16x32_bf16(a, b, c, 0, 0, 0)
#define PADR 520   // LDS row stride (elems): 1040B, 16B-aligned, 2-way banks

__device__ __forceinline__ float softplus_f(float v) {
    return (v > 20.f) ? v : log1pf(expf(v));
}
__device__ __forceinline__ float sigmoid_f(float v) {
    return 1.f / (1.f + expf(-v));
}

// ---- setup converters ----
__global__ __launch_bounds__(256) void f2b_kernel(
    const float* __restrict__ s, bf16* __restrict__ d, int n)
{
    int i = blockIdx.x * 256 + threadIdx.x;
    if (i < n) d[i] = __float2bfloat16(s[i]);
}
__global__ __launch_bounds__(256) void fcopy_kernel(
    const float* __restrict__ s, float* __restrict__ d, int n)
{
    int i = blockIdx.x * 256 + threadIdx.x;
    if (i < n) d[i] = s[i];
}

__global__ __launch_bounds__(256) void init_kernel(
    float* __restrict__ hprev, float* __restrict__ out)
{
    const int idx = blockIdx.x * 256 + threadIdx.x;
    if (idx < 262144) hprev[idx] = 0.f;
    if (idx < 3) out[idx] = 0.f;
}

// ---------------------------------------------------------------------------
// MFMA GEMM (unchanged from R3): C[M,N] = act(bias + sum_s A_s @ W_s^T)
// ---------------------------------------------------------------------------
__global__ __launch_bounds__(256) void mfma_gemm(
    const bf16* __restrict__ A0, int lda0, const bf16* __restrict__ W0, int ldw0, int K0,
    const bf16* __restrict__ A1, int lda1, const bf16* __restrict__ W1, int ldw1, int K1,
    const float* __restrict__ bias, int act,
    void* __restrict__ C, int ldc, int obf)
{
    const int tid = threadIdx.x;
    const int L = tid & 63, w = tid >> 6;
    const int m0 = blockIdx.y * 64 + (w & 1) * 32;
    const int n0 = blockIdx.x * 64 + (w >> 1) * 32;
    const int lr = L & 15;
    const int lk = (L >> 4) * 8;

    ffrag acc[2][2];
#pragma unroll
    for (int i = 0; i < 2; ++i)
#pragma unroll
        for (int j = 0; j < 2; ++j)
#pragma unroll
            for (int r = 0; r < 4; ++r) acc[i][j][r] = 0.f;

    for (int s = 0; s < 2; ++s) {
        const bf16* A = s ? A1 : A0;
        if (!A) break;
        const bf16* W = s ? W1 : W0;
        const int lda = s ? lda1 : lda0;
        const int ldw = s ? ldw1 : ldw0;
        const int K   = s ? K1 : K0;
        const bf16* a0p = A + (size_t)(m0 + lr) * lda + lk;
        const bf16* a1p = a0p + (size_t)16 * lda;
        const bf16* b0p = W + (size_t)(n0 + lr) * ldw + lk;
        const bf16* b1p = b0p + (size_t)16 * ldw;
        for (int k0 = 0; k0 < K; k0 += 32) {
            bfrag a0 = *(const bfrag*)(a0p + k0);
            bfrag a1 = *(const bfrag*)(a1p + k0);
            bfrag b0 = *(const bfrag*)(b0p + k0);
            bfrag b1 = *(const bfrag*)(b1p + k0);
            acc[0][0] = MFMA16(a0, b0, acc[0][0]);
            acc[0][1] = MFMA16(a0, b1, acc[0][1]);
            acc[1][0] = MFMA16(a1, b0, acc[1][0]);
            acc[1][1] = MFMA16(a1, b1, acc[1][1]);
        }
    }

#pragma unroll
    for (int i = 0; i < 2; ++i)
#pragma unroll
    for (int j = 0; j < 2; ++j)
#pragma unroll
    for (int r = 0; r < 4; ++r) {
        const int row = m0 + 16 * i + (L >> 4) * 4 + r;
        const int col = n0 + 16 * j + lr;
        float v = acc[i][j][r];
        if (bias) v += bias[col];
        if (act == 1) v = fmaxf(v, 0.f);
        else if (act == 2) { if (col >= 32) v = softplus_f(v); }
        else if (act == 3) { if (col < 64) v = fmaxf(v, 0.f); }
        const size_t g = (size_t)row * ldc + col;
        if (obf) ((bf16*)C)[g] = __float2bfloat16(v);
        else     ((float*)C)[g] = v;
    }
}

// ---------------------------------------------------------------------------
// seq_kernel: whole sequential phase of one chunk in ONE launch.
// 32 WGs x 256 thr; WG owns 16 batch rows. Per t: enc1, enc2, heads, z,
// phiz, gru — all row-local, LDS-resident intermediates.
// ---------------------------------------------------------------------------
__global__ __launch_bounds__(256) void seq_kernel(
    const bf16* __restrict__ phixC,   // [TC*512,512]
    const float* __restrict__ epsC,   // [TC,512,32]
    const bf16* __restrict__ ew1, const float* __restrict__ eb1,   // [512,1024]
    const bf16* __restrict__ ew2, const float* __restrict__ eb2,   // [512,512]
    const bf16* __restrict__ msw, const float* __restrict__ msb,   // [64,512]
    const bf16* __restrict__ pzw, const float* __restrict__ pzb,   // [512,32]
    const bf16* __restrict__ wih, const bf16* __restrict__ whh,    // [1536,1024],[1536,512]
    float* __restrict__ hprev,        // [512,512] f32 in/out (chunk handoff)
    float* __restrict__ emscC,        // [TC*512,64]
    bf16* __restrict__ phizC,         // [TC*512,512]
    bf16* __restrict__ hhC,           // [(TC+1)*512,512]
    int TC)
{
    __shared__ bf16 hb[16][PADR];     // h_t bf16
    __shared__ bf16 e1s[16][PADR];    // enc layer-1 out
    __shared__ bf16 pzs[16][PADR];    // ench, then phi_z
    __shared__ float msS[16][72];     // enc mean|std
    __shared__ bf16 zbS[16][40];      // z bf16

    const int tid = threadIdx.x;
    const int L = tid & 63, w = tid >> 6;
    const int m0 = blockIdx.x * 16;
    const int lr = L & 15;
    const int qk = L >> 4;
    const int lk = qk * 8;

    // prologue: h from hprev (f32) -> hb LDS + HH slot 0 (bf16)
    for (int i = tid; i < 16 * 512; i += 256) {
        const int r = i >> 9, c = i & 511;
        const float hv = hprev[(size_t)(m0 + r) * 512 + c];
        const bf16 hbv = __float2bfloat16(hv);
        hb[r][c] = hbv;
        hhC[(size_t)(m0 + r) * 512 + c] = hbv;
    }
    __syncthreads();

    for (int t = 0; t < TC; ++t) {
        const bf16* px = phixC + (size_t)t * 262144;
        const bf16* apx = px + (size_t)(m0 + lr) * 512 + lk;

        // ---- enc1: e1 = relu(b1 + phix@eW1a^T + h@eW1b^T), cols split 128/wave
        for (int nt = 0; nt < 8; ++nt) {
            const int col0 = 128 * w + 16 * nt;
            const bf16* bp = ew1 + (size_t)(col0 + lr) * 1024 + lk;
            ffrag acc; acc[0] = acc[1] = acc[2] = acc[3] = 0.f;
            for (int k0 = 0; k0 < 512; k0 += 32) {
                bfrag aX = *(const bfrag*)(apx + k0);
                bfrag aH = *(const bfrag*)(&hb[lr][k0 + lk]);
                bfrag bX = *(const bfrag*)(bp + k0);
                bfrag bH = *(const bfrag*)(bp + 512 + k0);
                acc = MFMA16(aX, bX, acc);
                acc = MFMA16(aH, bH, acc);
            }
#pragma unroll
            for (int r = 0; r < 4; ++r) {
                const int row = qk * 4 + r, col = col0 + lr;
                e1s[row][col] = __float2bfloat16(fmaxf(acc[r] + eb1[col], 0.f));
            }
        }
        __syncthreads();

        // ---- enc2: ench = relu(b2 + e1@eW2^T) -> pzs
        for (int nt = 0; nt < 8; ++nt) {
            const int col0 = 128 * w + 16 * nt;
            const bf16* bp = ew2 + (size_t)(col0 + lr) * 512 + lk;
            ffrag acc; acc[0] = acc[1] = acc[2] = acc[3] = 0.f;
            for (int k0 = 0; k0 < 512; k0 += 32) {
                bfrag a = *(const bfrag*)(&e1s[lr][k0 + lk]);
                bfrag b = *(const bfrag*)(bp + k0);
                acc = MFMA16(a, b, acc);
            }
#pragma unroll
            for (int r = 0; r < 4; ++r) {
                const int row = qk * 4 + r, col = col0 + lr;
                pzs[row][col] = __float2bfloat16(fmaxf(acc[r] + eb2[col], 0.f));
            }
        }
        __syncthreads();

        // ---- heads: ms = ench@msw^T + msb (softplus cols>=32); wave w -> 16 cols
        {
            const int col0 = 16 * w;
            const bf16* bp = msw + (size_t)(col0 + lr) * 512 + lk;
            ffrag acc; acc[0] = acc[1] = acc[2] = acc[3] = 0.f;
            for (int k0 = 0; k0 < 512; k0 += 32) {
                bfrag a = *(const bfrag*)(&pzs[lr][k0 + lk]);
                bfrag b = *(const bfrag*)(bp + k0);
                acc = MFMA16(a, b, acc);
            }
#pragma unroll
            for (int r = 0; r < 4; ++r) {
                const int row = qk * 4 + r, col = col0 + lr;
                float v = acc[r] + msb[col];
                if (col >= 32) v = softplus_f(v);
                msS[row][col] = v;
                emscC[((size_t)t * 512 + m0 + row) * 64 + col] = v;
            }
        }
        __syncthreads();

        // ---- z = eps*std + mean (x10 on cols 0..3) -> zb bf16
        {
            const int idx = tid * 2;
            const int r = idx >> 5, c0 = idx & 31;
#pragma unroll
            for (int j = 0; j < 2; ++j) {
                const int c = c0 + j;
                float zv = epsC[((size_t)t * 512 + m0 + r) * 32 + c] * msS[r][32 + c] + msS[r][c];
                if (c < 4) zv *= 10.f;
                zbS[r][c] = __float2bfloat16(zv);
            }
        }
        __syncthreads();

        // ---- phiz = relu(z@pzw^T + pzb) -> pzs (ench dead) + global
        for (int nt = 0; nt < 8; ++nt) {
            const int col0 = 128 * w + 16 * nt;
            bfrag b = *(const bfrag*)(pzw + (size_t)(col0 + lr) * 32 + lk);
            bfrag a = *(const bfrag*)(&zbS[lr][lk]);
            ffrag acc; acc[0] = acc[1] = acc[2] = acc[3] = 0.f;
            acc = MFMA16(a, b, acc);
#pragma unroll
            for (int r = 0; r < 4; ++r) {
                const int row = qk * 4 + r, col = col0 + lr;
                const float v = fmaxf(acc[r] + pzb[col], 0.f);
                const bf16 vb = __float2bfloat16(v);
                pzs[row][col] = vb;
                phizC[((size_t)t * 512 + m0 + row) * 512 + col] = vb;
            }
        }
        __syncthreads();

        // ---- gru: 8 j-tiles/wave; 6 accumulators; h update deferred to regs
        float hn[8][4];
        for (int jt = 0; jt < 8; ++jt) {
            const int j0 = 128 * w + 16 * jt;
            ffrag ax[3], ah[3];
#pragma unroll
            for (int g = 0; g < 3; ++g)
#pragma unroll
                for (int r = 0; r < 4; ++r) { ax[g][r] = 0.f; ah[g][r] = 0.f; }
            const bf16* wp0 = wih + (size_t)(j0 + lr) * 1024 + lk;
            const bf16* wp1 = wih + (size_t)(j0 + lr + 512) * 1024 + lk;
            const bf16* wp2 = wih + (size_t)(j0 + lr + 1024) * 1024 + lk;
            const bf16* hp0 = whh + (size_t)(j0 + lr) * 512 + lk;
            const bf16* hp1 = whh + (size_t)(j0 + lr + 512) * 512 + lk;
            const bf16* hp2 = whh + (size_t)(j0 + lr + 1024) * 512 + lk;
            for (int k0 = 0; k0 < 512; k0 += 32) {
                bfrag aX = *(const bfrag*)(apx + k0);
                bfrag aZ = *(const bfrag*)(&pzs[lr][k0 + lk]);
                bfrag aH = *(const bfrag*)(&hb[lr][k0 + lk]);
                ax[0] = MFMA16(aX, *(const bfrag*)(wp0 + k0), ax[0]);
                ax[0] = MFMA16(aZ, *(const bfrag*)(wp0 + 512 + k0), ax[0]);
                ah[0] = MFMA16(aH, *(const bfrag*)(hp0 + k0), ah[0]);
                ax[1] = MFMA16(aX, *(const bfrag*)(wp1 + k0), ax[1]);
                ax[1] = MFMA16(aZ, *(const bfrag*)(wp1 + 512 + k0), ax[1]);
                ah[1] = MFMA16(aH, *(const bfrag*)(hp1 + k0), ah[1]);
                ax[2] = MFMA16(aX, *(const bfrag*)(wp2 + k0), ax[2]);
                ax[2] = MFMA16(aZ, *(const bfrag*)(wp2 + 512 + k0), ax[2]);
                ah[2] = MFMA16(aH, *(const bfrag*)(hp2 + k0), ah[2]);
            }
#pragma unroll
            for (int r = 0; r < 4; ++r) {
                const int row = qk * 4 + r, col = j0 + lr;
                const size_t gidx = (size_t)(m0 + row) * 512 + col;
                const float hv = hprev[gidx];
                const float rg = sigmoid_f(ax[0][r] + ah[0][r]);
                const float zg = sigmoid_f(ax[1][r] + ah[1][r]);
                const float nn = tanhf(ax[2][r] + rg * ah[2][r]);
                const float hnew = (1.f - zg) * nn + zg * hv;
                hprev[gidx] = hnew;
                hhC[((size_t)(t + 1) * 512 + m0 + row) * 512 + col] = __float2bfloat16(hnew);
                hn[jt][r] = hnew;
            }
        }
        __syncthreads();   // all waves done reading hb/pzs
#pragma unroll
        for (int jt = 0; jt < 8; ++jt)
#pragma unroll
            for (int r = 0; r < 4; ++r)
                hb[qk * 4 + r][128 * w + 16 * jt + lr] = __float2bfloat16(hn[jt][r]);
        __syncthreads();
    }
}

// ---------------------------------------------------------------------------
// KLD (unchanged)
// ---------------------------------------------------------------------------
__global__ __launch_bounds__(256) void kld_kernel(
    const float* __restrict__ emsc, const float* __restrict__ pms,
    float* __restrict__ out)
{
    const size_t p0 = (size_t)blockIdx.x * 1024 + threadIdx.x;
    float acc = 0.f;
#pragma unroll
    for (int rep = 0; rep < 4; ++rep) {
        const size_t p = p0 + (size_t)rep * 256;
        const size_t i = p >> 5; const int c = p & 31;
        const float m1 = emsc[i * 64 + c];
        const float s1 = fmaxf(emsc[i * 64 + 32 + c], 1e-9f);
        const float m2 = pms[i * 64 + c];
        const float s2 = fmaxf(pms[i * 64 + 32 + c], 1e-9f);
        const float dm = m1 - m2;
        acc += 2.f * (logf(s2) - logf(s1)) + (s1 * s1 + dm * dm) / (s2 * s2) - 1.f;
    }
    for (int off = 32; off > 0; off >>= 1) acc += __shfl_down(acc, off);
    __shared__ float tmp[4];
    if ((threadIdx.x & 63) == 0) tmp[threadIdx.x >> 6] = acc;
    __syncthreads();
    if (threadIdx.x == 0)
        atomicAdd(out + 1, 0.5f * (tmp[0] + tmp[1] + tmp[2] + tmp[3]));
}

// ---------------------------------------------------------------------------
// final (unchanged): ddc [rows,128] = (relu(dec_mean1)|dec_std_raw)
// ---------------------------------------------------------------------------
__global__ __launch_bounds__(256) void final_kernel(
    const float* __restrict__ ddc,
    const float* __restrict__ W2, const float* __restrict__ b2,
    const float* __restrict__ x,
    float* __restrict__ sums, float* __restrict__ outDM)
{
    __shared__ float Dh[32][64];
    __shared__ float W2s[64][65];
    const int tid = threadIdx.x;
    const size_t r0 = (size_t)blockIdx.x * 32;

    for (int i = tid; i < 32 * 64; i += 256)
        Dh[i >> 6][i & 63] = ddc[(r0 + (i >> 6)) * 128 + (i & 63)];
    for (int i = tid; i < 64 * 64; i += 256) W2s[i >> 6][i & 63] = W2[i];
    __syncthreads();

    float rec = 0.f, nll = 0.f;
#pragma unroll
    for (int rep = 0; rep < 8; ++rep) {
        const int idx = rep * 256 + tid;
        const int r = idx >> 6, j = idx & 63;
        float acc = b2[j];
#pragma unroll 8
        for (int k = 0; k < 64; ++k) acc += Dh[r][k] * W2s[j][k];
        const size_t g = (r0 + r) * 64 + j;
        const float xv = x[g];
        const float sd = softplus_f(ddc[(r0 + r) * 128 + 64 + j]);
        outDM[g] = acc;
        const float d = xv - acc;
        rec += d * d;
        nll += logf(sd + 1e-5f) + 0.9189385332046727f + d * d / (2.f * sd * sd);
    }
    for (int off = 32; off > 0; off >>= 1) {
        rec += __shfl_down(rec, off);
        nll += __shfl_down(nll, off);
    }
    __shared__ float rr[4], nn[4];
    if ((tid & 63) == 0) { rr[tid >> 6] = rec; nn[tid >> 6] = nll; }
    __syncthreads();
    if (tid == 0) {
        atomicAdd(sums + 0, rr[0] + rr[1] + rr[2] + rr[3]);
        atomicAdd(sums + 2, nn[0] + nn[1] + nn[2] + nn[3]);
    }
}

// ---------------------------------------------------------------------------

static void gemm(hipStream_t s, int M, int N,
                 const bf16* A0, int lda0, const bf16* W0, int ldw0, int K0,
                 const bf16* A1, int lda1, const bf16* W1, int ldw1, int K1,
                 const float* bias, int act, void* C, int ldc, int obf)
{
    dim3 g(N / 64, M / 64), b(256);
    hipLaunchKernelGGL(mfma_gemm, g, b, 0, s,
                       A0, lda0, W0, ldw0, K0, A1, lda1, W1, ldw1, K1,
                       bias, act, C, ldc, obf);
}

static void f2b(hipStream_t s, const float* src, bf16* dst, int n) {
    hipLaunchKernelGGL(f2b_kernel, dim3((n + 255) / 256), dim3(256), 0, s, src, dst, n);
}
static void fcp(hipStream_t s, const float* src, float* dst, int n) {
    hipLaunchKernelGGL(fcopy_kernel, dim3((n + 255) / 256), dim3(256), 0, s, src, dst, n);
}

// bf16-weight element offsets within WB
#define O_PXW1 0
#define O_PXW2 32768
#define O_PZW  294912
#define O_EW1  311296
#define O_EW2  835584
#define O_MSW  1097728
#define O_PRW  1130496
#define O_PMSW 1392640
#define O_DW1  1425408
#define O_DW2  1949696
#define O_DDW  2211840
#define O_GWIH 2277376
#define O_GWHH 3850240

static size_t ws_needed(int tc) {
    return 27624448ull + (size_t)tc * 2490368ull;
}

extern "C" void kernel_launch(void* const* d_in, const int* in_sizes, int n_in,
                              void* d_out, int out_size, void* d_ws, size_t ws_size,
                              hipStream_t stream)
{
    const float* x_in   = (const float*)d_in[0];
    const float* eps_in = (const float*)d_in[1];
    const float* pxW1 = (const float*)d_in[2];  const float* pxb1 = (const float*)d_in[3];
    const float* pxW2 = (const float*)d_in[4];  const float* pxb2 = (const float*)d_in[5];
    const float* pzW  = (const float*)d_in[6];  const float* pzb  = (const float*)d_in[7];
    const float* eW1  = (const float*)d_in[8];  const float* eb1  = (const float*)d_in[9];
    const float* eW2  = (const float*)d_in[10]; const float* eb2  = (const float*)d_in[11];
    const float* emW  = (const float*)d_in[12];
    const float* esW  = (const float*)d_in[14];
    const float* prW  = (const float*)d_in[16]; const float* prb  = (const float*)d_in[17];
    const float* pmW  = (const float*)d_in[18];
    const float* psW  = (const float*)d_in[20];
    const float* dW1  = (const float*)d_in[22]; const float* db1  = (const float*)d_in[23];
    const float* dW2  = (const float*)d_in[24]; const float* db2  = (const float*)d_in[25];
    const float* dsW  = (const float*)d_in[26];
    const float* dmW1 = (const float*)d_in[28];
    const float* dmW2 = (const float*)d_in[30]; const float* dmb2 = (const float*)d_in[31];
    const float* gWih = (const float*)d_in[32]; const float* gWhh = (const float*)d_in[33];
    const float* emb  = (const float*)d_in[13]; const float* esb  = (const float*)d_in[15];
    const float* pmb  = (const float*)d_in[19]; const float* psb  = (const float*)d_in[21];
    const float* dmb1 = (const float*)d_in[29]; const float* dsb  = (const float*)d_in[27];

    float* out = (float*)d_out;
    char* ws = (char*)d_ws;

    int TC = 1;
    const int cands[9] = {256, 128, 64, 32, 16, 8, 4, 2, 1};
    for (int i = 0; i < 9; ++i)
        if (ws_needed(cands[i]) <= ws_size) { TC = cands[i]; break; }
    const int NCH = 256 / TC;

    // ---- workspace map ----
    bf16*  WB    = (bf16*)(ws);                         // 9,273,344 B
    float* BB    = (float*)(ws + 9273344ull);           // 1,024 B
    bf16*  XBF   = (bf16*)(ws + 9274368ull);            // 16,777,216 B
    float* HPREV = (float*)(ws + 26051584ull);          // 1,048,576 B
    bf16*  HH    = (bf16*)(ws + 27100160ull);           // (TC+1)*524,288 B
    size_t off = 27100160ull + (size_t)(TC + 1) * 524288ull;
    bf16*  R1    = (bf16*)(ws + off); off += (size_t)TC * 524288ull;
    bf16*  R2    = (bf16*)(ws + off); off += (size_t)TC * 524288ull;  // PHIX / DECH
    bf16*  PHIZC = (bf16*)(ws + off); off += (size_t)TC * 524288ull;
    float* EMSC  = (float*)(ws + off); off += (size_t)TC * 131072ull;
    float* U     = (float*)(ws + off);                  // TC*262,144 B (PMS then DDC)

    // ---- setup: weight/bias/x conversion ----
    f2b(stream, pxW1, WB + O_PXW1, 32768);
    f2b(stream, pxW2, WB + O_PXW2, 262144);
    f2b(stream, pzW,  WB + O_PZW,  16384);
    f2b(stream, eW1,  WB + O_EW1,  524288);
    f2b(stream, eW2,  WB + O_EW2,  262144);
    f2b(stream, emW,  WB + O_MSW,  16384);
    f2b(stream, esW,  WB + O_MSW + 16384, 16384);
    f2b(stream, prW,  WB + O_PRW,  262144);
    f2b(stream, pmW,  WB + O_PMSW, 16384);
    f2b(stream, psW,  WB + O_PMSW + 16384, 16384);
    f2b(stream, dW1,  WB + O_DW1,  524288);
    f2b(stream, dW2,  WB + O_DW2,  262144);
    f2b(stream, dmW1, WB + O_DDW,  32768);
    f2b(stream, dsW,  WB + O_DDW + 32768, 32768);
    f2b(stream, gWih, WB + O_GWIH, 1572864);
    f2b(stream, gWhh, WB + O_GWHH, 786432);
    f2b(stream, x_in, XBF, 8388608);
    fcp(stream, emb,  BB + 0,   32);
    fcp(stream, esb,  BB + 32,  32);
    fcp(stream, pmb,  BB + 64,  32);
    fcp(stream, psb,  BB + 96,  32);
    fcp(stream, dmb1, BB + 128, 64);
    fcp(stream, dsb,  BB + 192, 64);

    hipLaunchKernelGGL(init_kernel, dim3(1024), dim3(256), 0, stream, HPREV, out);

    for (int c = 0; c < NCH; ++c) {
        const int cs = c * TC;
        const int MR = TC * 512;

        // ---- pre: phi_x MLP for the chunk ----
        gemm(stream, MR, 512, XBF + (size_t)cs * 32768, 64, WB + O_PXW1, 64, 64,
             nullptr, 0, nullptr, 0, 0, pxb1, 1, R1, 512, 1);
        gemm(stream, MR, 512, R1, 512, WB + O_PXW2, 512, 512,
             nullptr, 0, nullptr, 0, 0, pxb2, 1, R2, 512, 1);

        // ---- sequential phase: ONE launch for TC steps ----
        hipLaunchKernelGGL(seq_kernel, dim3(32), dim3(256), 0, stream,
                           R2, eps_in + (size_t)cs * 16384,
                           WB + O_EW1, eb1, WB + O_EW2, eb2,
                           WB + O_MSW, BB, WB + O_PZW, pzb,
                           WB + O_GWIH, WB + O_GWHH,
                           HPREV, EMSC, PHIZC, HH, TC);

        // ---- post: prior + KLD ----
        gemm(stream, MR, 512, HH, 512, WB + O_PRW, 512, 512,
             nullptr, 0, nullptr, 0, 0, prb, 1, R1, 512, 1);
        gemm(stream, MR, 64, R1, 512, WB + O_PMSW, 512, 512,
             nullptr, 0, nullptr, 0, 0, BB + 64, 2, U, 64, 0);
        hipLaunchKernelGGL(kld_kernel, dim3(TC * 16), dim3(256), 0, stream,
                           EMSC, U, out);

        // ---- post: dec + NLL/rec ----
        gemm(stream, MR, 512, PHIZC, 512, WB + O_DW1, 1024, 512,
             HH, 512, WB + O_DW1 + 512, 1024, 512, db1, 1, R1, 512, 1);
        gemm(stream, MR, 512, R1, 512, WB + O_DW2, 512, 512,
             nullptr, 0, nullptr, 0, 0, db2, 1, R2, 512, 1);
        gemm(stream, MR, 128, R2, 512, WB + O_DDW, 512, 512,
             nullptr, 0, nullptr, 0, 0, BB + 128, 3, U, 128, 0);
        hipLaunchKernelGGL(final_kernel, dim3(MR / 32), dim3(256), 0, stream,
                           U, dmW2, dmb2, x_in + (size_t)cs * 32768,
                           out, out + 3 + (size_t)cs * 32768);
    }
}

// Round 5
// 46612.564 us; speedup vs baseline: 2.0367x; 2.0367x over previous
//
#include <hip/hip_runtime.h>
#include <hip/hip_bf16.h>
#include <math.h>

// ---------------------------------------------------------------------------
// VRNN on MI355X — Round 5: column-split per-step stage pipeline.
// R4 lesson: row-local WGs each stream the full 6.1 MB weight set -> capped
// by per-CU load throughput (~4-50 GB/s) -> 360 us/step. Fix: split every
// stage GEMM across many WGs (stream order = barrier), weights L2-hot and
// fetched once per step per XCD. phi_x contribution to enc1 hoisted (PE1).
// 6 launches/step: enc1h, enc2, heads-z-phiz, GX(2seg), GH, gates.
// ---------------------------------------------------------------------------

typedef __attribute__((ext_vector_type(8))) short bfrag;   // 8 x bf16
typedef __attribute__((ext_vector_type(4))) float ffrag;   // 4 x f32
typedef __hip_bfloat16 bf16;

#define MFMA16(a,b,c) __builtin_amdgcn_mfma_f32_16x16x32_bf16(a, b, c, 0, 0, 0)

__device__ __forceinline__ float softplus_f(float v) {
    return (v > 20.f) ? v : log1pf(expf(v));
}
__device__ __forceinline__ float sigmoid_f(float v) {
    return 1.f / (1.f + expf(-v));
}

// ---- setup converters ----
__global__ __launch_bounds__(256) void f2b_kernel(
    const float* __restrict__ s, bf16* __restrict__ d, int n)
{
    int i = blockIdx.x * 256 + threadIdx.x;
    if (i < n) d[i] = __float2bfloat16(s[i]);
}
// strided/sliced convert: d[r*dld+c] = bf16(s[r*sld + soff + c])
__global__ __launch_bounds__(256) void f2bs_kernel(
    const float* __restrict__ s, int sld, int soff,
    bf16* __restrict__ d, int dld, int rows, int cols)
{
    int i = blockIdx.x * 256 + threadIdx.x;
    if (i < rows * cols) {
        int r = i / cols, c = i - r * cols;
        d[(size_t)r * dld + c] = __float2bfloat16(s[(size_t)r * sld + soff + c]);
    }
}
__global__ __launch_bounds__(256) void fcopy_kernel(
    const float* __restrict__ s, float* __restrict__ d, int n)
{
    int i = blockIdx.x * 256 + threadIdx.x;
    if (i < n) d[i] = s[i];
}

__global__ __launch_bounds__(256) void init_kernel(
    float* __restrict__ hprev, bf16* __restrict__ hh0, float* __restrict__ out)
{
    const int idx = blockIdx.x * 256 + threadIdx.x;
    if (idx < 262144) { hprev[idx] = 0.f; hh0[idx] = __float2bfloat16(0.f); }
    if (idx < 3) out[idx] = 0.f;
}

__global__ __launch_bounds__(256) void snap_kernel(
    const bf16* __restrict__ src, bf16* __restrict__ dst)
{
    const int idx = blockIdx.x * 256 + threadIdx.x;
    dst[idx] = src[idx];
}

// ---------------------------------------------------------------------------
// gemm512: C[M,N] = act(bias + D + sum_s A_s @ W_s^T). 512 thr, tile 128x128,
// wave tile 64x32. M%128==0, N%128==0, K%32==0. A,W bf16; D optional bf16
// addend; out f32 or bf16. act: 0 none, 1 relu, 3 relu on col<64.
// ---------------------------------------------------------------------------
__global__ __launch_bounds__(512) void gemm512(
    const bf16* __restrict__ A0, int lda0, const bf16* __restrict__ W0, int ldw0, int K0,
    const bf16* __restrict__ A1, int lda1, const bf16* __restrict__ W1, int ldw1, int K1,
    const bf16* __restrict__ D, int ldd,
    const float* __restrict__ bias, int act,
    void* __restrict__ C, int ldc, int obf)
{
    const int tid = threadIdx.x;
    const int L = tid & 63, w = tid >> 6;
    const int m0 = blockIdx.y * 128 + (w & 1) * 64;
    const int n0 = blockIdx.x * 128 + (w >> 1) * 32;
    const int lr = L & 15;
    const int qk = L >> 4;
    const int lk = qk * 8;

    ffrag acc[4][2];
#pragma unroll
    for (int i = 0; i < 4; ++i)
#pragma unroll
        for (int j = 0; j < 2; ++j)
#pragma unroll
            for (int r = 0; r < 4; ++r) acc[i][j][r] = 0.f;

    for (int s = 0; s < 2; ++s) {
        const bf16* A = s ? A1 : A0;
        if (!A) break;
        const bf16* W = s ? W1 : W0;
        const int lda = s ? lda1 : lda0;
        const int ldw = s ? ldw1 : ldw0;
        const int K   = s ? K1 : K0;
        const bf16* ap = A + (size_t)(m0 + lr) * lda + lk;
        const bf16* bp = W + (size_t)(n0 + lr) * ldw + lk;
        for (int k0 = 0; k0 < K; k0 += 32) {
            bfrag a[4], b[2];
#pragma unroll
            for (int i = 0; i < 4; ++i)
                a[i] = *(const bfrag*)(ap + (size_t)(16 * i) * lda + k0);
#pragma unroll
            for (int j = 0; j < 2; ++j)
                b[j] = *(const bfrag*)(bp + (size_t)(16 * j) * ldw + k0);
#pragma unroll
            for (int i = 0; i < 4; ++i)
#pragma unroll
                for (int j = 0; j < 2; ++j)
                    acc[i][j] = MFMA16(a[i], b[j], acc[i][j]);
        }
    }

#pragma unroll
    for (int i = 0; i < 4; ++i)
#pragma unroll
    for (int j = 0; j < 2; ++j)
#pragma unroll
    for (int r = 0; r < 4; ++r) {
        const int row = m0 + 16 * i + qk * 4 + r;
        const int col = n0 + 16 * j + lr;
        float v = acc[i][j][r];
        if (D)    v += __bfloat162float(D[(size_t)row * ldd + col]);
        if (bias) v += bias[col];
        if (act == 1) v = fmaxf(v, 0.f);
        else if (act == 3) { if (col < 64) v = fmaxf(v, 0.f); }
        const size_t g = (size_t)row * ldc + col;
        if (obf) ((bf16*)C)[g] = __float2bfloat16(v);
        else     ((float*)C)[g] = v;
    }
}

// ---------------------------------------------------------------------------
// old 64x64-tile GEMM kept for N=64 (pms). act 2 = softplus on col>=32.
// ---------------------------------------------------------------------------
__global__ __launch_bounds__(256) void mfma_gemm(
    const bf16* __restrict__ A0, int lda0, const bf16* __restrict__ W0, int ldw0, int K0,
    const float* __restrict__ bias, int act,
    void* __restrict__ C, int ldc, int obf)
{
    const int tid = threadIdx.x;
    const int L = tid & 63, w = tid >> 6;
    const int m0 = blockIdx.y * 64 + (w & 1) * 32;
    const int n0 = blockIdx.x * 64 + (w >> 1) * 32;
    const int lr = L & 15;
    const int lk = (L >> 4) * 8;

    ffrag acc[2][2];
#pragma unroll
    for (int i = 0; i < 2; ++i)
#pragma unroll
        for (int j = 0; j < 2; ++j)
#pragma unroll
            for (int r = 0; r < 4; ++r) acc[i][j][r] = 0.f;

    const bf16* a0p = A0 + (size_t)(m0 + lr) * lda0 + lk;
    const bf16* a1p = a0p + (size_t)16 * lda0;
    const bf16* b0p = W0 + (size_t)(n0 + lr) * ldw0 + lk;
    const bf16* b1p = b0p + (size_t)16 * ldw0;
    for (int k0 = 0; k0 < K0; k0 += 32) {
        bfrag a0 = *(const bfrag*)(a0p + k0);
        bfrag a1 = *(const bfrag*)(a1p + k0);
        bfrag b0 = *(const bfrag*)(b0p + k0);
        bfrag b1 = *(const bfrag*)(b1p + k0);
        acc[0][0] = MFMA16(a0, b0, acc[0][0]);
        acc[0][1] = MFMA16(a0, b1, acc[0][1]);
        acc[1][0] = MFMA16(a1, b0, acc[1][0]);
        acc[1][1] = MFMA16(a1, b1, acc[1][1]);
    }

#pragma unroll
    for (int i = 0; i < 2; ++i)
#pragma unroll
    for (int j = 0; j < 2; ++j)
#pragma unroll
    for (int r = 0; r < 4; ++r) {
        const int row = m0 + 16 * i + (L >> 4) * 4 + r;
        const int col = n0 + 16 * j + lr;
        float v = acc[i][j][r];
        if (bias) v += bias[col];
        if (act == 1) v = fmaxf(v, 0.f);
        else if (act == 2) { if (col >= 32) v = softplus_f(v); }
        const size_t g = (size_t)row * ldc + col;
        if (obf) ((bf16*)C)[g] = __float2bfloat16(v);
        else     ((float*)C)[g] = v;
    }
}

// ---------------------------------------------------------------------------
// hzp: heads (ms = ench@msw^T + msb, softplus col>=32) -> EMSC + LDS,
// z = eps*std+mean (x10 cols 0..3), phiz = relu(z@pzw^T + pzb) -> PHIZC.
// 8 WGs x 256 thr, 64 rows each.
// ---------------------------------------------------------------------------
__global__ __launch_bounds__(256) void hzp_kernel(
    const bf16* __restrict__ ench,     // [512,512]
    const bf16* __restrict__ msw,      // [64,512]
    const float* __restrict__ msb,     // [64]
    const float* __restrict__ eps_t,   // [512,32]
    const bf16* __restrict__ pzw,      // [512,32]
    const float* __restrict__ pzb,     // [512]
    float* __restrict__ emsc_t,        // [512,64]
    bf16* __restrict__ phiz_t)         // [512,512]
{
    __shared__ float msS[64][68];
    __shared__ bf16 zb[64][40];
    const int tid = threadIdx.x;
    const int L = tid & 63, w = tid >> 6;   // 4 waves
    const int m0 = blockIdx.x * 64;
    const int lr = L & 15;
    const int qk = L >> 4;
    const int lk = qk * 8;

    // heads: wave w -> cols [16w,16w+16), rows m0..m0+64 (4 row-tiles)
    {
        const int col0 = 16 * w;
        const bf16* bp = msw + (size_t)(col0 + lr) * 512 + lk;
        ffrag acc[4];
#pragma unroll
        for (int i = 0; i < 4; ++i)
#pragma unroll
            for (int r = 0; r < 4; ++r) acc[i][r] = 0.f;
        const bf16* ap = ench + (size_t)(m0 + lr) * 512 + lk;
        for (int k0 = 0; k0 < 512; k0 += 32) {
            bfrag b = *(const bfrag*)(bp + k0);
#pragma unroll
            for (int i = 0; i < 4; ++i) {
                bfrag a = *(const bfrag*)(ap + (size_t)(16 * i) * 512 + k0);
                acc[i] = MFMA16(a, b, acc[i]);
            }
        }
#pragma unroll
        for (int i = 0; i < 4; ++i)
#pragma unroll
        for (int r = 0; r < 4; ++r) {
            const int row = 16 * i + qk * 4 + r;
            const int col = col0 + lr;
            float v = acc[i][r] + msb[col];
            if (col >= 32) v = softplus_f(v);
            msS[row][col] = v;
            emsc_t[(size_t)(m0 + row) * 64 + col] = v;
        }
    }
    __syncthreads();

    // z: 64 rows x 32 cols, 8 elems/thread
    {
        const int row = tid >> 2, c0 = (tid & 3) * 8;
#pragma unroll
        for (int j = 0; j < 8; ++j) {
            const int c = c0 + j;
            float zv = eps_t[(size_t)(m0 + row) * 32 + c] * msS[row][32 + c] + msS[row][c];
            if (c < 4) zv *= 10.f;
            zb[row][c] = __float2bfloat16(zv);
        }
    }
    __syncthreads();

    // phiz: wave w -> cols [128w,128w+128), K=32
    for (int nt = 0; nt < 8; ++nt) {
        const int col0 = 128 * w + 16 * nt;
        bfrag b = *(const bfrag*)(pzw + (size_t)(col0 + lr) * 32 + lk);
#pragma unroll
        for (int i = 0; i < 4; ++i) {
            bfrag a = *(const bfrag*)(&zb[16 * i + lr][lk]);
            ffrag c;
#pragma unroll
            for (int r = 0; r < 4; ++r) c[r] = 0.f;
            c = MFMA16(a, b, c);
#pragma unroll
            for (int r = 0; r < 4; ++r) {
                const int row = 16 * i + qk * 4 + r;
                const int col = col0 + lr;
                const float v = fmaxf(c[r] + pzb[col], 0.f);
                phiz_t[(size_t)(m0 + row) * 512 + col] = __float2bfloat16(v);
            }
        }
    }
}

// ---------------------------------------------------------------------------
// gates: h_new = (1-z)*n + z*h, n = tanh(xn + r*hn). GX/GH f32 [512,1536].
// ---------------------------------------------------------------------------
__global__ __launch_bounds__(256) void gates_kernel(
    const float* __restrict__ GX, const float* __restrict__ GH,
    float* __restrict__ hprev, bf16* __restrict__ h_next)
{
    const int idx = blockIdx.x * 256 + threadIdx.x;   // 262144
    const int m = idx >> 9, j = idx & 511;
    const size_t b = (size_t)m * 1536 + j;
    const float r  = sigmoid_f(GX[b] + GH[b]);
    const float zg = sigmoid_f(GX[b + 512] + GH[b + 512]);
    const float n  = tanhf(GX[b + 1024] + r * GH[b + 1024]);
    const float hv = hprev[idx];
    const float hnew = (1.f - zg) * n + zg * hv;
    hprev[idx] = hnew;
    h_next[idx] = __float2bfloat16(hnew);
}

// ---------------------------------------------------------------------------
// KLD: emsc/pms [M,64] = (mean | std). -> atomicAdd(out+1)
// ---------------------------------------------------------------------------
__global__ __launch_bounds__(256) void kld_kernel(
    const float* __restrict__ emsc, const float* __restrict__ pms,
    float* __restrict__ out)
{
    const size_t p0 = (size_t)blockIdx.x * 1024 + threadIdx.x;
    float acc = 0.f;
#pragma unroll
    for (int rep = 0; rep < 4; ++rep) {
        const size_t p = p0 + (size_t)rep * 256;
        const size_t i = p >> 5; const int c = p & 31;
        const float m1 = emsc[i * 64 + c];
        const float s1 = fmaxf(emsc[i * 64 + 32 + c], 1e-9f);
        const float m2 = pms[i * 64 + c];
        const float s2 = fmaxf(pms[i * 64 + 32 + c], 1e-9f);
        const float dm = m1 - m2;
        acc += 2.f * (logf(s2) - logf(s1)) + (s1 * s1 + dm * dm) / (s2 * s2) - 1.f;
    }
    for (int off = 32; off > 0; off >>= 1) acc += __shfl_down(acc, off);
    __shared__ float tmp[4];
    if ((threadIdx.x & 63) == 0) tmp[threadIdx.x >> 6] = acc;
    __syncthreads();
    if (threadIdx.x == 0)
        atomicAdd(out + 1, 0.5f * (tmp[0] + tmp[1] + tmp[2] + tmp[3]));
}

// ---------------------------------------------------------------------------
// final: ddc [rows,128] = (relu(dec_mean1) | dec_std_raw). dec_mean2 GEMM
// (64x64 fp32) + dec_means + rec/nll. 32 rows/block.
// ---------------------------------------------------------------------------
__global__ __launch_bounds__(256) void final_kernel(
    const float* __restrict__ ddc,
    const float* __restrict__ W2, const float* __restrict__ b2,
    const float* __restrict__ x,
    float* __restrict__ sums, float* __restrict__ outDM)
{
    __shared__ float Dh[32][64];
    __shared__ float W2s[64][65];
    const int tid = threadIdx.x;
    const size_t r0 = (size_t)blockIdx.x * 32;

    for (int i = tid; i < 32 * 64; i += 256)
        Dh[i >> 6][i & 63] = ddc[(r0 + (i >> 6)) * 128 + (i & 63)];
    for (int i = tid; i < 64 * 64; i += 256) W2s[i >> 6][i & 63] = W2[i];
    __syncthreads();

    float rec = 0.f, nll = 0.f;
#pragma unroll
    for (int rep = 0; rep < 8; ++rep) {
        const int idx = rep * 256 + tid;
        const int r = idx >> 6, j = idx & 63;
        float acc = b2[j];
#pragma unroll 8
        for (int k = 0; k < 64; ++k) acc += Dh[r][k] * W2s[j][k];
        const size_t g = (r0 + r) * 64 + j;
        const float xv = x[g];
        const float sd = softplus_f(ddc[(r0 + r) * 128 + 64 + j]);
        outDM[g] = acc;
        const float d = xv - acc;
        rec += d * d;
        nll += logf(sd + 1e-5f) + 0.9189385332046727f + d * d / (2.f * sd * sd);
    }
    for (int off = 32; off > 0; off >>= 1) {
        rec += __shfl_down(rec, off);
        nll += __shfl_down(nll, off);
    }
    __shared__ float rr[4], nn[4];
    if ((tid & 63) == 0) { rr[tid >> 6] = rec; nn[tid >> 6] = nll; }
    __syncthreads();
    if (tid == 0) {
        atomicAdd(sums + 0, rr[0] + rr[1] + rr[2] + rr[3]);
        atomicAdd(sums + 2, nn[0] + nn[1] + nn[2] + nn[3]);
    }
}

// ---------------------------------------------------------------------------

static void g512(hipStream_t s, int M, int N,
                 const bf16* A0, int lda0, const bf16* W0, int ldw0, int K0,
                 const bf16* A1, int lda1, const bf16* W1, int ldw1, int K1,
                 const bf16* D, int ldd,
                 const float* bias, int act, void* C, int ldc, int obf)
{
    dim3 g(N / 128, M / 128), b(512);
    hipLaunchKernelGGL(gemm512, g, b, 0, s,
                       A0, lda0, W0, ldw0, K0, A1, lda1, W1, ldw1, K1,
                       D, ldd, bias, act, C, ldc, obf);
}

static void f2bs(hipStream_t s, const float* src, int sld, int soff,
                 bf16* dst, int dld, int rows, int cols) {
    int n = rows * cols;
    hipLaunchKernelGGL(f2bs_kernel, dim3((n + 255) / 256), dim3(256), 0, s,
                       src, sld, soff, dst, dld, rows, cols);
}
static void f2b(hipStream_t s, const float* src, bf16* dst, int n) {
    hipLaunchKernelGGL(f2b_kernel, dim3((n + 255) / 256), dim3(256), 0, s, src, dst, n);
}
static void fcp(hipStream_t s, const float* src, float* dst, int n) {
    hipLaunchKernelGGL(fcopy_kernel, dim3((n + 255) / 256), dim3(256), 0, s, src, dst, n);
}

// bf16-weight element offsets within WB
#define O_PXW1 0
#define O_PXW2 32768
#define O_PZW  294912
#define O_W1A  311296
#define O_W1B  573440
#define O_EW2  835584
#define O_MSW  1097728
#define O_PRW  1130496
#define O_PMSW 1392640
#define O_DW1  1425408
#define O_DW2  1949696
#define O_DDW  2211840
#define O_WIH  2277376
#define O_WHH  3850240

static size_t ws_needed(int tc) {
    return 34964480ull + (size_t)tc * 3014656ull;
}

extern "C" void kernel_launch(void* const* d_in, const int* in_sizes, int n_in,
                              void* d_out, int out_size, void* d_ws, size_t ws_size,
                              hipStream_t stream)
{
    const float* x_in   = (const float*)d_in[0];
    const float* eps_in = (const float*)d_in[1];
    const float* pxW1 = (const float*)d_in[2];  const float* pxb1 = (const float*)d_in[3];
    const float* pxW2 = (const float*)d_in[4];  const float* pxb2 = (const float*)d_in[5];
    const float* pzW  = (const float*)d_in[6];  const float* pzb  = (const float*)d_in[7];
    const float* eW1  = (const float*)d_in[8];  const float* eb1  = (const float*)d_in[9];
    const float* eW2  = (const float*)d_in[10]; const float* eb2  = (const float*)d_in[11];
    const float* emW  = (const float*)d_in[12]; const float* emb  = (const float*)d_in[13];
    const float* esW  = (const float*)d_in[14]; const float* esb  = (const float*)d_in[15];
    const float* prW  = (const float*)d_in[16]; const float* prb  = (const float*)d_in[17];
    const float* pmW  = (const float*)d_in[18]; const float* pmb  = (const float*)d_in[19];
    const float* psW  = (const float*)d_in[20]; const float* psb  = (const float*)d_in[21];
    const float* dW1  = (const float*)d_in[22]; const float* db1  = (const float*)d_in[23];
    const float* dW2  = (const float*)d_in[24]; const float* db2  = (const float*)d_in[25];
    const float* dsW  = (const float*)d_in[26]; const float* dsb  = (const float*)d_in[27];
    const float* dmW1 = (const float*)d_in[28]; const float* dmb1 = (const float*)d_in[29];
    const float* dmW2 = (const float*)d_in[30]; const float* dmb2 = (const float*)d_in[31];
    const float* gWih = (const float*)d_in[32]; const float* gWhh = (const float*)d_in[33];

    float* out = (float*)d_out;
    char* ws = (char*)d_ws;

    int TC = 1;
    const int cands[9] = {256, 128, 64, 32, 16, 8, 4, 2, 1};
    for (int i = 0; i < 9; ++i)
        if (ws_needed(cands[i]) <= ws_size) { TC = cands[i]; break; }
    const int NCH = 256 / TC;

    // ---- workspace map (bytes) ----
    bf16*  WB    = (bf16*)(ws);                         // 9,273,344
    float* BB    = (float*)(ws + 9273344ull);           // 1,024
    bf16*  XBF   = (bf16*)(ws + 9274368ull);            // 16,777,216
    float* HPREV = (float*)(ws + 26051584ull);          // 1,048,576
    bf16*  E1    = (bf16*)(ws + 27100160ull);           // 524,288
    bf16*  ENCH  = (bf16*)(ws + 27624448ull);           // 524,288
    float* GX    = (float*)(ws + 28148736ull);          // 3,145,728
    float* GH    = (float*)(ws + 31294464ull);          // 3,145,728
    bf16*  HH    = (bf16*)(ws + 34440192ull);           // (TC+1)*524,288
    size_t off = 34440192ull + (size_t)(TC + 1) * 524288ull;
    bf16*  PHIX  = (bf16*)(ws + off); off += (size_t)TC * 524288ull;  // phi_x / dec_h
    bf16*  PE1   = (bf16*)(ws + off); off += (size_t)TC * 524288ull;  // enc1 phi_x partial
    bf16*  PHIZC = (bf16*)(ws + off); off += (size_t)TC * 524288ull;
    bf16*  R1    = (bf16*)(ws + off); off += (size_t)TC * 524288ull;  // G1/prior_h/dec_eh
    float* EMSC  = (float*)(ws + off); off += (size_t)TC * 131072ull;
    float* U     = (float*)(ws + off);                  // TC*262,144 (pms then ddc)

    // ---- setup: weight/bias/x conversion ----
    f2b(stream, pxW1, WB + O_PXW1, 32768);
    f2b(stream, pxW2, WB + O_PXW2, 262144);
    f2b(stream, pzW,  WB + O_PZW,  16384);
    f2bs(stream, eW1, 1024, 0,   WB + O_W1A, 512, 512, 512);
    f2bs(stream, eW1, 1024, 512, WB + O_W1B, 512, 512, 512);
    f2b(stream, eW2,  WB + O_EW2,  262144);
    f2b(stream, emW,  WB + O_MSW,  16384);
    f2b(stream, esW,  WB + O_MSW + 16384, 16384);
    f2b(stream, prW,  WB + O_PRW,  262144);
    f2b(stream, pmW,  WB + O_PMSW, 16384);
    f2b(stream, psW,  WB + O_PMSW + 16384, 16384);
    f2b(stream, dW1,  WB + O_DW1,  524288);
    f2b(stream, dW2,  WB + O_DW2,  262144);
    f2b(stream, dmW1, WB + O_DDW,  32768);
    f2b(stream, dsW,  WB + O_DDW + 32768, 32768);
    f2b(stream, gWih, WB + O_WIH, 1572864);
    f2b(stream, gWhh, WB + O_WHH, 786432);
    f2b(stream, x_in, XBF, 8388608);
    fcp(stream, emb,  BB + 0,   32);
    fcp(stream, esb,  BB + 32,  32);
    fcp(stream, pmb,  BB + 64,  32);
    fcp(stream, psb,  BB + 96,  32);
    fcp(stream, dmb1, BB + 128, 64);
    fcp(stream, dsb,  BB + 192, 64);

    hipLaunchKernelGGL(init_kernel, dim3(1024), dim3(256), 0, stream, HPREV, HH, out);

    for (int c = 0; c < NCH; ++c) {
        const int cs = c * TC;
        const int MR = TC * 512;

        // ---- pre: phi_x MLP + enc1 phi_x partial ----
        g512(stream, MR, 512, XBF + (size_t)cs * 32768, 64, WB + O_PXW1, 64, 64,
             nullptr, 0, nullptr, 0, 0, nullptr, 0, pxb1, 1, R1, 512, 1);
        g512(stream, MR, 512, R1, 512, WB + O_PXW2, 512, 512,
             nullptr, 0, nullptr, 0, 0, nullptr, 0, pxb2, 1, PHIX, 512, 1);
        g512(stream, MR, 512, PHIX, 512, WB + O_W1A, 512, 512,
             nullptr, 0, nullptr, 0, 0, nullptr, 0, nullptr, 0, PE1, 512, 1);

        if (c > 0)
            hipLaunchKernelGGL(snap_kernel, dim3(1024), dim3(256), 0, stream,
                               HH + (size_t)TC * 262144, HH);

        // ---- sequential steps (6 launches each) ----
        for (int lt = 0; lt < TC; ++lt) {
            const int t = cs + lt;
            const bf16* HHt = HH + (size_t)lt * 262144;
            // enc1 (h part) + PE1 partial
            g512(stream, 512, 512, HHt, 512, WB + O_W1B, 512, 512,
                 nullptr, 0, nullptr, 0, 0,
                 PE1 + (size_t)lt * 262144, 512, eb1, 1, E1, 512, 1);
            // enc2
            g512(stream, 512, 512, E1, 512, WB + O_EW2, 512, 512,
                 nullptr, 0, nullptr, 0, 0, nullptr, 0, eb2, 1, ENCH, 512, 1);
            // heads + z + phiz
            hipLaunchKernelGGL(hzp_kernel, dim3(8), dim3(256), 0, stream,
                               ENCH, WB + O_MSW, BB, eps_in + (size_t)t * 16384,
                               WB + O_PZW, pzb,
                               EMSC + (size_t)lt * 32768, PHIZC + (size_t)lt * 262144);
            // gx = phix@WihX^T + phiz@WihZ^T
            g512(stream, 512, 1536, PHIX + (size_t)lt * 262144, 512, WB + O_WIH, 1024, 512,
                 PHIZC + (size_t)lt * 262144, 512, WB + O_WIH + 512, 1024, 512,
                 nullptr, 0, nullptr, 0, GX, 1536, 0);
            // gh = h@Whh^T
            g512(stream, 512, 1536, HHt, 512, WB + O_WHH, 512, 512,
                 nullptr, 0, nullptr, 0, 0, nullptr, 0, nullptr, 0, GH, 1536, 0);
            // gates -> h
            hipLaunchKernelGGL(gates_kernel, dim3(1024), dim3(256), 0, stream,
                               GX, GH, HPREV, HH + (size_t)(lt + 1) * 262144);
        }

        // ---- post: prior + KLD ----
        g512(stream, MR, 512, HH, 512, WB + O_PRW, 512, 512,
             nullptr, 0, nullptr, 0, 0, nullptr, 0, prb, 1, R1, 512, 1);
        {
            dim3 g(1, MR / 64), b(256);
            hipLaunchKernelGGL(mfma_gemm, g, b, 0, stream,
                               R1, 512, WB + O_PMSW, 512, 512, BB + 64, 2, U, 64, 0);
        }
        hipLaunchKernelGGL(kld_kernel, dim3(TC * 16), dim3(256), 0, stream,
                           EMSC, U, out);

        // ---- post: dec + NLL/rec ----
        g512(stream, MR, 512, PHIZC, 512, WB + O_DW1, 1024, 512,
             HH, 512, WB + O_DW1 + 512, 1024, 512,
             nullptr, 0, db1, 1, R1, 512, 1);
        g512(stream, MR, 512, R1, 512, WB + O_DW2, 512, 512,
             nullptr, 0, nullptr, 0, 0, nullptr, 0, db2, 1, PHIX, 512, 1);
        g512(stream, MR, 128, PHIX, 512, WB + O_DDW, 512, 512,
             nullptr, 0, nullptr, 0, 0, nullptr, 0, BB + 128, 3, U, 128, 0);
        hipLaunchKernelGGL(final_kernel, dim3(MR / 32), dim3(256), 0, stream,
                           U, dmW2, dmb2, x_in + (size_t)cs * 32768,
                           out, out + 3 + (size_t)cs * 32768);
    }
}